// Round 7
// baseline (17767.706 us; speedup 1.0000x reference)
//
#include <hip/hip_runtime.h>

typedef unsigned long long ull;

// ---------------- constants ----------------
constexpr int T_STEPS = 512;
constexpr int IN_DIM  = 1024;
constexpr int H       = 2048;
constexpr int H2      = 4096;
constexpr int OUT_DIM = 1024;

constexpr int NWG  = 256;    // cooperative grid: 1 wg per CU
constexpr int NTHR = 1024;   // 16 waves per wg

// workspace layout (in floats)
constexpr size_t OFF_XI   = 0;                                    // [512][2048]
constexpr size_t OFF_P    = OFF_XI + (size_t)T_STEPS * H;         // [512][4096]
constexpr size_t OFF_HBUF = OFF_P  + (size_t)T_STEPS * H2;        // [513][2048]
constexpr size_t OFF_A    = OFF_HBUF + (size_t)(T_STEPS + 1) * H; // [4096]
constexpr size_t OFF_Y    = OFF_A + H2;                           // [4096]
constexpr size_t OFF_BAR  = OFF_Y + H2;                           // barrier words (2 KB)

// ---------------- coherent (LLC-level) access helpers: sc0 sc1, NO cache invalidation
__device__ __forceinline__ ull load_coh8(const ull* p) {
    return __hip_atomic_load(p, __ATOMIC_RELAXED, __HIP_MEMORY_SCOPE_AGENT);
}
__device__ __forceinline__ void store_cohf(float* p, float v) {
    __hip_atomic_store(p, v, __ATOMIC_RELAXED, __HIP_MEMORY_SCOPE_AGENT);
}

// ---------------- two-level fence-free grid barrier ----------------
// bars[g*16], g=0..7 : group words (gen<<32|cnt), 128B apart
// bars[128]          : master word  (gen<<32|cnt) — gen is the broadcast release
__device__ __forceinline__ void grid_barrier_fixed(ull* bars) {
    __syncthreads();   // drains vmcnt: block's coherent stores are at the LLC
    if (threadIdx.x == 0) {
        ull* gw = bars + ((blockIdx.x & 7) << 4);
        ull* mw = bars + 128;
        // read gen BEFORE arrival (after arrival the barrier may complete instantly)
        unsigned gen = (unsigned)(__hip_atomic_load(mw, __ATOMIC_RELAXED,
                                                    __HIP_MEMORY_SCOPE_AGENT) >> 32);
        ull old = __hip_atomic_fetch_add(gw, 1ull, __ATOMIC_RELAXED,
                                         __HIP_MEMORY_SCOPE_AGENT);
        bool released = false;
        if ((unsigned)(old & 0xffffffffu) == 31u) {
            // last of group: self-reset group word, arrive at master
            __hip_atomic_fetch_add(gw, (1ull << 32) - 32ull, __ATOMIC_RELAXED,
                                   __HIP_MEMORY_SCOPE_AGENT);
            ull mo = __hip_atomic_fetch_add(mw, 1ull, __ATOMIC_RELAXED,
                                            __HIP_MEMORY_SCOPE_AGENT);
            if ((unsigned)(mo & 0xffffffffu) == 7u) {
                // release: reset master count AND bump gen in ONE atomic
                __hip_atomic_fetch_add(mw, (1ull << 32) - 8ull, __ATOMIC_RELAXED,
                                       __HIP_MEMORY_SCOPE_AGENT);
                released = true;
            }
        }
        if (!released) {
            while ((unsigned)(__hip_atomic_load(mw, __ATOMIC_RELAXED,
                                                __HIP_MEMORY_SCOPE_AGENT) >> 32) == gen)
                __builtin_amdgcn_s_sleep(1);
        }
    }
    __syncthreads();
}

__device__ __forceinline__ float wave_reduce(float s) {
    #pragma unroll
    for (int o = 32; o; o >>= 1) s += __shfl_down(s, o, 64);
    return s;
}

__device__ __forceinline__ float dot4(float4 a, float4 b) {
    return a.x*b.x + a.y*b.y + a.z*b.z + a.w*b.w;
}

// keep-alive: force v materialized in VGPRs at this program point (rule #17)
#define KEEP4(v) asm volatile("" :: "v"((v).x), "v"((v).y), "v"((v).z), "v"((v).w))

union U8 { ull u; float2 f; };

// ---------------- sequential recurrence (persistent cooperative kernel) ----------------
__global__ void __launch_bounds__(NTHR, 4) rnn_seq(
    const float* __restrict__ l1w,   // [4096][4096]
    const float* __restrict__ l2w,   // [4096][4096]
    const float* __restrict__ l2b,   // [4096]
    const float* __restrict__ xhw,   // [2048][4096]
    const float* __restrict__ xhb,   // [2048]
    const float* __restrict__ XI,    // [512][2048]
    const float* __restrict__ P,     // [512][4096]
    float* __restrict__ hbuf,        // [513][2048]
    float* __restrict__ abuf,        // [4096]
    float* __restrict__ ybuf,        // [4096]
    ull* __restrict__ bar)
{
    const int wg   = blockIdx.x;
    const int tid  = threadIdx.x;
    const int wave = tid >> 6;
    const int lane = tid & 63;

    __shared__ float smem[38928];
    float* wsA = smem;            // 32768 floats: stage-A weight rows (pinned)
    float* hz  = smem + 32768;    // 2048 floats:  h_t
    float* az  = smem + 34816;    // 4096 floats:  a / z vector
    float* sc  = smem + 38912;    // 16 floats:    stage-C partials

    // ---- one-time: pin stage-A (l1_w[:, 2048:]) rows for this wg into LDS
    #pragma unroll
    for (int i = 0; i < 8; ++i) {
        const int idx = tid + (i << 10);
        const int w   = idx >> 9;
        const int c4  = idx & 511;
        float4 v = *(const float4*)(l1w + (size_t)((wg << 4) + w) * H2 + H + (c4 << 2));
        *(float4*)(wsA + (w << 11) + (c4 << 2)) = v;
    }
    __syncthreads();

    const int rA = (wg << 4) + wave;                       // stage A/B row
    const float* __restrict__ wrowB = l2w + (size_t)rA * H2;
    const int wC    = wave & 7;
    const int halfC = wave >> 3;
    const int rC    = (wg << 3) + wC;                      // stage C row (2 waves/row)
    const float* __restrict__ wrowC = xhw + (size_t)rC * H2 + (halfC ? H : 0);

    // ---- prologue: prefetch stage-B row into registers (t-invariant addresses)
    float4 wb[16];
    #pragma unroll
    for (int i = 0; i < 16; ++i)
        wb[i] = *(const float4*)(wrowB + (((i << 6) + lane) << 2));
    #pragma unroll
    for (int i = 0; i < 16; ++i) KEEP4(wb[i]);

    for (int t = 0; t < T_STEPS; ++t) {
        const float* __restrict__ xi = XI + (size_t)t * H;
        const float* __restrict__ p  = P  + (size_t)t * H2;

        // ---- stage h_t into LDS (coherent 8B loads)
        {
            const ull* hsrc = (const ull*)(hbuf + (size_t)t * H);
            U8 u; u.u = load_coh8(hsrc + tid);
            *(float2*)(hz + (tid << 1)) = u.f;
        }
        __syncthreads();

        // ---- Stage A: a[rA] = relu(P_t[rA] + wsA_row . h)   (all-LDS)
        float s = 0.f;
        #pragma unroll
        for (int i = 0; i < 8; ++i) {
            const int c4 = ((i << 6) + lane) << 2;
            float4 w4 = *(const float4*)(wsA + (wave << 11) + c4);
            float4 h4 = *(const float4*)(hz + c4);
            s += dot4(w4, h4);
        }
        s = wave_reduce(s);
        if (lane == 0) store_cohf(abuf + rA, fmaxf(p[rA] + s, 0.f));

        grid_barrier_fixed(bar);

        // ---- stage a-vector into LDS (coherent 8B loads)
        {
            const ull* a8 = (const ull*)abuf;
            U8 u0; u0.u = load_coh8(a8 + tid);
            U8 u1; u1.u = load_coh8(a8 + tid + 1024);
            *(float2*)(az + (tid << 1))        = u0.f;
            *(float2*)(az + (tid << 1) + 2048) = u1.f;
        }
        __syncthreads();

        // ---- issue stage-C weight loads; B-compute covers their latency
        float4 wc[8];
        #pragma unroll
        for (int i = 0; i < 8; ++i)
            wc[i] = *(const float4*)(wrowC + (((i << 6) + lane) << 2));

        // ---- Stage B: y[rA] = l2b[rA] + wrowB . a   (weights already in regs)
        s = 0.f;
        #pragma unroll
        for (int i = 0; i < 16; ++i) {
            const int c4 = ((i << 6) + lane) << 2;
            float4 a4 = *(const float4*)(az + c4);
            s += dot4(wb[i], a4);
        }
        s = wave_reduce(s);
        if (lane == 0) store_cohf(ybuf + rA, l2b[rA] + s);

        #pragma unroll
        for (int i = 0; i < 8; ++i) KEEP4(wc[i]);

        grid_barrier_fixed(bar);

        // ---- stage z = relu(xh + y) into LDS (reuse az)
        {
            const int c = tid << 2;
            U8 y0; y0.u = load_coh8((const ull*)ybuf + (tid << 1));
            U8 y1; y1.u = load_coh8((const ull*)ybuf + (tid << 1) + 1);
            float4 xv = (tid < 512) ? *(const float4*)(xi + c)
                                    : *(const float4*)(hz + c - H);
            float4 zv;
            zv.x = fmaxf(xv.x + y0.f.x, 0.f);
            zv.y = fmaxf(xv.y + y0.f.y, 0.f);
            zv.z = fmaxf(xv.z + y1.f.x, 0.f);
            zv.w = fmaxf(xv.w + y1.f.y, 0.f);
            *(float4*)(az + c) = zv;
        }
        __syncthreads();

        // ---- issue next-step stage-B weight reloads; C-compute covers them,
        //      and they stay live across barrier3 + h-stage + stage A.
        #pragma unroll
        for (int i = 0; i < 16; ++i)
            wb[i] = *(const float4*)(wrowB + (((i << 6) + lane) << 2));

        // ---- Stage C: h'[rC] = xhb[rC] + wrowC-half . z-half   (2 waves/row)
        s = 0.f;
        {
            const int base = halfC ? H : 0;
            #pragma unroll
            for (int i = 0; i < 8; ++i) {
                const int c4 = (((i << 6) + lane) << 2) + base;
                float4 z4 = *(const float4*)(az + c4);
                s += dot4(wc[i], z4);
            }
        }
        s = wave_reduce(s);
        if (lane == 0) sc[wave] = s;
        __syncthreads();
        if (wave < 8 && lane == 0)
            store_cohf(hbuf + (size_t)(t + 1) * H + rC, sc[wC] + sc[wC + 8] + xhb[rC]);

        #pragma unroll
        for (int i = 0; i < 16; ++i) KEEP4(wb[i]);

        grid_barrier_fixed(bar);
    }
}

// ---------------- batched GEMM: C[M,N] = A[M,K] @ B[N,K]^T + bias ----------------
__global__ void __launch_bounds__(256) gemm_nt(
    const float* __restrict__ A, int lda,
    const float* __restrict__ B, int ldb,
    const float* __restrict__ bias,
    float* __restrict__ C, int ldc, int K)
{
    __shared__ float As[32][129];
    __shared__ float Bs[32][65];
    const int tid = threadIdx.x;
    const int m0 = blockIdx.y * 128, n0 = blockIdx.x * 64;
    const int tx = tid & 15, ty = tid >> 4;

    float acc[8][4] = {};
    for (int k0 = 0; k0 < K; k0 += 32) {
        #pragma unroll
        for (int i = 0; i < 4; ++i) {
            const int idx = tid + i * 256;
            const int r = idx >> 3, c4 = idx & 7;
            float4 v = *(const float4*)(A + (size_t)(m0 + r) * lda + k0 + c4 * 4);
            As[c4*4+0][r] = v.x; As[c4*4+1][r] = v.y; As[c4*4+2][r] = v.z; As[c4*4+3][r] = v.w;
        }
        #pragma unroll
        for (int i = 0; i < 2; ++i) {
            const int idx = tid + i * 256;
            const int r = idx >> 3, c4 = idx & 7;
            float4 v = *(const float4*)(B + (size_t)(n0 + r) * ldb + k0 + c4 * 4);
            Bs[c4*4+0][r] = v.x; Bs[c4*4+1][r] = v.y; Bs[c4*4+2][r] = v.z; Bs[c4*4+3][r] = v.w;
        }
        __syncthreads();
        #pragma unroll
        for (int k = 0; k < 32; ++k) {
            float a[8], b[4];
            #pragma unroll
            for (int i = 0; i < 8; ++i) a[i] = As[k][ty * 8 + i];
            #pragma unroll
            for (int j = 0; j < 4; ++j) b[j] = Bs[k][tx * 4 + j];
            #pragma unroll
            for (int i = 0; i < 8; ++i)
                #pragma unroll
                for (int j = 0; j < 4; ++j)
                    acc[i][j] += a[i] * b[j];
        }
        __syncthreads();
    }
    const float4 bv = *(const float4*)(bias + n0 + tx * 4);
    #pragma unroll
    for (int i = 0; i < 8; ++i) {
        const int m = m0 + ty * 8 + i;
        float4 o;
        o.x = acc[i][0] + bv.x; o.y = acc[i][1] + bv.y;
        o.z = acc[i][2] + bv.z; o.w = acc[i][3] + bv.w;
        *(float4*)(C + (size_t)m * ldc + n0 + tx * 4) = o;
    }
}

// ---------------- launch ----------------
extern "C" void kernel_launch(void* const* d_in, const int* in_sizes, int n_in,
                              void* d_out, int out_size, void* d_ws, size_t ws_size,
                              hipStream_t stream) {
    const float* x      = (const float*)d_in[0];
    const float* h0     = (const float*)d_in[1];
    const float* inp_w  = (const float*)d_in[2];
    const float* inp_b  = (const float*)d_in[3];
    const float* l1_w   = (const float*)d_in[4];
    const float* l1_b   = (const float*)d_in[5];
    const float* l2_w   = (const float*)d_in[6];
    const float* l2_b   = (const float*)d_in[7];
    const float* xh2h_w = (const float*)d_in[8];
    const float* xh2h_b = (const float*)d_in[9];
    const float* out_w  = (const float*)d_in[10];
    const float* out_b  = (const float*)d_in[11];
    float* out = (float*)d_out;

    float* ws   = (float*)d_ws;
    float* XI   = ws + OFF_XI;
    float* P    = ws + OFF_P;
    float* hbuf = ws + OFF_HBUF;
    float* abuf = ws + OFF_A;
    float* ybuf = ws + OFF_Y;
    ull*   bar  = (ull*)(ws + OFF_BAR);

    hipMemsetAsync(bar, 0, 2048, stream);
    hipMemcpyAsync(hbuf, h0, H * sizeof(float), hipMemcpyDeviceToDevice, stream);

    // XI = x @ inp_w^T + inp_b        [512,2048]
    gemm_nt<<<dim3(H / 64, T_STEPS / 128), 256, 0, stream>>>(
        x, IN_DIM, inp_w, IN_DIM, inp_b, XI, H, IN_DIM);
    // P = XI @ l1_w[:, :2048]^T + l1_b   [512,4096]
    gemm_nt<<<dim3(H2 / 64, T_STEPS / 128), 256, 0, stream>>>(
        XI, H, l1_w, H2, l1_b, P, H2, H);

    {
        void* args[] = {
            (void*)&l1_w, (void*)&l2_w, (void*)&l2_b,
            (void*)&xh2h_w, (void*)&xh2h_b,
            (void*)&XI, (void*)&P, (void*)&hbuf, (void*)&abuf, (void*)&ybuf,
            (void*)&bar
        };
        hipLaunchCooperativeKernel((const void*)rnn_seq, dim3(NWG), dim3(NTHR),
                                   args, 0, stream);
    }

    // ys = H' @ out_w^T + out_b       [512,1024]
    gemm_nt<<<dim3(OUT_DIM / 64, T_STEPS / 128), 256, 0, stream>>>(
        hbuf + H, H, out_w, H, out_b, out, OUT_DIM, H);
    hipMemcpyAsync(out + (size_t)T_STEPS * OUT_DIM, hbuf + (size_t)T_STEPS * H,
                   H * sizeof(float), hipMemcpyDeviceToDevice, stream);
}

// Round 8
// 7404.547 us; speedup vs baseline: 2.3996x; 2.3996x over previous
//
#include <hip/hip_runtime.h>

typedef unsigned long long ull;

// ---------------- constants ----------------
constexpr int T_STEPS = 512;
constexpr int IN_DIM  = 1024;
constexpr int H       = 2048;
constexpr int H2      = 4096;
constexpr int OUT_DIM = 1024;

constexpr int NWG  = 256;    // cooperative grid: 1 wg per CU
constexpr int NTHR = 1024;   // 16 waves per wg

// workspace layout (in floats)
constexpr size_t OFF_XI   = 0;                                    // [512][2048]
constexpr size_t OFF_P    = OFF_XI + (size_t)T_STEPS * H;         // [512][4096]
constexpr size_t OFF_HBUF = OFF_P  + (size_t)T_STEPS * H2;        // [513][2048]
constexpr size_t OFF_A    = OFF_HBUF + (size_t)(T_STEPS + 1) * H; // [4096]
constexpr size_t OFF_Y    = OFF_A + H2;                           // [4096]
constexpr size_t OFF_BAR  = OFF_Y + H2;                           // barrier words (2 KB)

// ---------------- coherent (LLC-level) access helpers: sc0 sc1, NO cache invalidation
__device__ __forceinline__ ull load_coh8(const ull* p) {
    return __hip_atomic_load(p, __ATOMIC_RELAXED, __HIP_MEMORY_SCOPE_AGENT);
}
__device__ __forceinline__ void store_cohf(float* p, float v) {
    __hip_atomic_store(p, v, __ATOMIC_RELAXED, __HIP_MEMORY_SCOPE_AGENT);
}

// ---------------- two-level grid barrier, MONOTONIC counters (no resets, no races)
// bars[g*16], g=0..7 : group arrival counters (128 B apart)
// bars[128]          : master counter; barrier instance `inst` done when mw == 8*inst
// All words only ever incremented -> no reset/arrival ordering hazard.
// 1536 instances/launch, u64 -> no overflow. memset-0 start state is instance 1.
__device__ __forceinline__ void grid_barrier(ull* bars, unsigned inst) {
    __syncthreads();   // compiler drains vmcnt before s_barrier: block's stores are at LLC
    if (threadIdx.x == 0) {
        ull* gw = bars + ((blockIdx.x & 7) << 4);
        ull* mw = bars + 128;
        ull old = __hip_atomic_fetch_add(gw, 1ull, __ATOMIC_RELAXED,
                                         __HIP_MEMORY_SCOPE_AGENT);
        if (old == (ull)inst * 32ull - 1ull) {     // last arrival of this group
            __hip_atomic_fetch_add(mw, 1ull, __ATOMIC_RELAXED,
                                   __HIP_MEMORY_SCOPE_AGENT);
        }
        while (__hip_atomic_load(mw, __ATOMIC_RELAXED,
                                 __HIP_MEMORY_SCOPE_AGENT) < (ull)inst * 8ull)
            __builtin_amdgcn_s_sleep(1);
    }
    __syncthreads();
}

__device__ __forceinline__ float wave_reduce(float s) {
    #pragma unroll
    for (int o = 32; o; o >>= 1) s += __shfl_down(s, o, 64);
    return s;
}

__device__ __forceinline__ float dot4(float4 a, float4 b) {
    return a.x*b.x + a.y*b.y + a.z*b.z + a.w*b.w;
}

union U8 { ull u; float2 f; };

// ---------------- sequential recurrence (persistent cooperative kernel) ----------------
// Identical to the round-4 kernel (10.96 ms, FETCH~0) except the barrier.
__global__ void __launch_bounds__(NTHR, 4) rnn_seq(
    const float* __restrict__ l1w,   // [4096][4096]
    const float* __restrict__ l2w,   // [4096][4096]
    const float* __restrict__ l2b,   // [4096]
    const float* __restrict__ xhw,   // [2048][4096]
    const float* __restrict__ xhb,   // [2048]
    const float* __restrict__ XI,    // [512][2048]
    const float* __restrict__ P,     // [512][4096]
    float* __restrict__ hbuf,        // [513][2048]
    float* __restrict__ abuf,        // [4096]
    float* __restrict__ ybuf,        // [4096]
    ull* __restrict__ bar)
{
    const int wg   = blockIdx.x;
    const int tid  = threadIdx.x;
    const int wave = tid >> 6;
    const int lane = tid & 63;

    __shared__ float smem[38928];
    float* wsA = smem;            // 32768 floats: stage-A weight rows (pinned)
    float* hz  = smem + 32768;    // 2048 floats:  h_t
    float* az  = smem + 34816;    // 4096 floats:  a / z vector
    float* sc  = smem + 38912;    // 16 floats:    stage-C partials

    // ---- one-time: pin stage-A (l1_w[:, 2048:]) rows for this wg into LDS
    #pragma unroll
    for (int i = 0; i < 8; ++i) {
        const int idx = tid + (i << 10);
        const int w   = idx >> 9;
        const int c4  = idx & 511;
        float4 v = *(const float4*)(l1w + (size_t)((wg << 4) + w) * H2 + H + (c4 << 2));
        *(float4*)(wsA + (w << 11) + (c4 << 2)) = v;
    }
    __syncthreads();

    const int rA = (wg << 4) + wave;                       // stage A/B row
    const float* __restrict__ wrowB = l2w + (size_t)rA * H2;
    const int wC    = wave & 7;
    const int halfC = wave >> 3;
    const int rC    = (wg << 3) + wC;                      // stage C row (2 waves/row)
    const float* __restrict__ wrowC = xhw + (size_t)rC * H2 + (halfC ? H : 0);

    unsigned inst = 0;   // barrier instance counter (same sequence in every block)

    for (int t = 0; t < T_STEPS; ++t) {
        const float* __restrict__ xi = XI + (size_t)t * H;
        const float* __restrict__ p  = P  + (size_t)t * H2;

        // ---- stage h_t into LDS (coherent 8B loads)
        {
            const ull* hsrc = (const ull*)(hbuf + (size_t)t * H);
            U8 u; u.u = load_coh8(hsrc + tid);
            *(float2*)(hz + (tid << 1)) = u.f;
        }
        __syncthreads();

        // ---- Stage A: a[rA] = relu(P_t[rA] + wsA_row . h)   (all-LDS)
        float s = 0.f;
        #pragma unroll
        for (int i = 0; i < 8; ++i) {
            const int c4 = ((i << 6) + lane) << 2;
            float4 w4 = *(const float4*)(wsA + (wave << 11) + c4);
            float4 h4 = *(const float4*)(hz + c4);
            s += dot4(w4, h4);
        }
        s = wave_reduce(s);
        if (lane == 0) store_cohf(abuf + rA, fmaxf(p[rA] + s, 0.f));

        // prefetch full stage-B row (16 float4 in flight; fills during barrier)
        float4 wb[16];
        #pragma unroll
        for (int i = 0; i < 16; ++i)
            wb[i] = *(const float4*)(wrowB + (((i << 6) + lane) << 2));

        grid_barrier(bar, ++inst);

        // ---- stage a-vector into LDS (coherent 8B loads)
        {
            const ull* a8 = (const ull*)abuf;
            U8 u0; u0.u = load_coh8(a8 + tid);
            U8 u1; u1.u = load_coh8(a8 + tid + 1024);
            *(float2*)(az + (tid << 1))        = u0.f;
            *(float2*)(az + (tid << 1) + 2048) = u1.f;
        }
        __syncthreads();

        // ---- Stage B: y[rA] = l2b[rA] + wrowB . a
        s = 0.f;
        #pragma unroll
        for (int i = 0; i < 16; ++i) {
            const int c4 = ((i << 6) + lane) << 2;
            float4 a4 = *(const float4*)(az + c4);
            s += dot4(wb[i], a4);
        }
        s = wave_reduce(s);
        if (lane == 0) store_cohf(ybuf + rA, l2b[rA] + s);

        // prefetch stage-C half-row (8 float4)
        float4 wc[8];
        #pragma unroll
        for (int i = 0; i < 8; ++i)
            wc[i] = *(const float4*)(wrowC + (((i << 6) + lane) << 2));

        grid_barrier(bar, ++inst);

        // ---- stage z = relu(xh + y) into LDS (reuse az)
        {
            const int c = tid << 2;
            U8 y0; y0.u = load_coh8((const ull*)ybuf + (tid << 1));
            U8 y1; y1.u = load_coh8((const ull*)ybuf + (tid << 1) + 1);
            float4 xv = (tid < 512) ? *(const float4*)(xi + c)
                                    : *(const float4*)(hz + c - H);
            float4 zv;
            zv.x = fmaxf(xv.x + y0.f.x, 0.f);
            zv.y = fmaxf(xv.y + y0.f.y, 0.f);
            zv.z = fmaxf(xv.z + y1.f.x, 0.f);
            zv.w = fmaxf(xv.w + y1.f.y, 0.f);
            *(float4*)(az + c) = zv;
        }
        __syncthreads();

        // ---- Stage C: h'[rC] = xhb[rC] + wrowC-half . z-half   (2 waves/row)
        s = 0.f;
        {
            const int base = halfC ? H : 0;
            #pragma unroll
            for (int i = 0; i < 8; ++i) {
                const int c4 = (((i << 6) + lane) << 2) + base;
                float4 z4 = *(const float4*)(az + c4);
                s += dot4(wc[i], z4);
            }
        }
        s = wave_reduce(s);
        if (lane == 0) sc[wave] = s;
        __syncthreads();
        if (wave < 8 && lane == 0)
            store_cohf(hbuf + (size_t)(t + 1) * H + rC, sc[wC] + sc[wC + 8] + xhb[rC]);

        grid_barrier(bar, ++inst);
    }
}

// ---------------- batched GEMM: C[M,N] = A[M,K] @ B[N,K]^T + bias ----------------
__global__ void __launch_bounds__(256) gemm_nt(
    const float* __restrict__ A, int lda,
    const float* __restrict__ B, int ldb,
    const float* __restrict__ bias,
    float* __restrict__ C, int ldc, int K)
{
    __shared__ float As[32][129];
    __shared__ float Bs[32][65];
    const int tid = threadIdx.x;
    const int m0 = blockIdx.y * 128, n0 = blockIdx.x * 64;
    const int tx = tid & 15, ty = tid >> 4;

    float acc[8][4] = {};
    for (int k0 = 0; k0 < K; k0 += 32) {
        #pragma unroll
        for (int i = 0; i < 4; ++i) {
            const int idx = tid + i * 256;
            const int r = idx >> 3, c4 = idx & 7;
            float4 v = *(const float4*)(A + (size_t)(m0 + r) * lda + k0 + c4 * 4);
            As[c4*4+0][r] = v.x; As[c4*4+1][r] = v.y; As[c4*4+2][r] = v.z; As[c4*4+3][r] = v.w;
        }
        #pragma unroll
        for (int i = 0; i < 2; ++i) {
            const int idx = tid + i * 256;
            const int r = idx >> 3, c4 = idx & 7;
            float4 v = *(const float4*)(B + (size_t)(n0 + r) * ldb + k0 + c4 * 4);
            Bs[c4*4+0][r] = v.x; Bs[c4*4+1][r] = v.y; Bs[c4*4+2][r] = v.z; Bs[c4*4+3][r] = v.w;
        }
        __syncthreads();
        #pragma unroll
        for (int k = 0; k < 32; ++k) {
            float a[8], b[4];
            #pragma unroll
            for (int i = 0; i < 8; ++i) a[i] = As[k][ty * 8 + i];
            #pragma unroll
            for (int j = 0; j < 4; ++j) b[j] = Bs[k][tx * 4 + j];
            #pragma unroll
            for (int i = 0; i < 8; ++i)
                #pragma unroll
                for (int j = 0; j < 4; ++j)
                    acc[i][j] += a[i] * b[j];
        }
        __syncthreads();
    }
    const float4 bv = *(const float4*)(bias + n0 + tx * 4);
    #pragma unroll
    for (int i = 0; i < 8; ++i) {
        const int m = m0 + ty * 8 + i;
        float4 o;
        o.x = acc[i][0] + bv.x; o.y = acc[i][1] + bv.y;
        o.z = acc[i][2] + bv.z; o.w = acc[i][3] + bv.w;
        *(float4*)(C + (size_t)m * ldc + n0 + tx * 4) = o;
    }
}

// ---------------- launch ----------------
extern "C" void kernel_launch(void* const* d_in, const int* in_sizes, int n_in,
                              void* d_out, int out_size, void* d_ws, size_t ws_size,
                              hipStream_t stream) {
    const float* x      = (const float*)d_in[0];
    const float* h0     = (const float*)d_in[1];
    const float* inp_w  = (const float*)d_in[2];
    const float* inp_b  = (const float*)d_in[3];
    const float* l1_w   = (const float*)d_in[4];
    const float* l1_b   = (const float*)d_in[5];
    const float* l2_w   = (const float*)d_in[6];
    const float* l2_b   = (const float*)d_in[7];
    const float* xh2h_w = (const float*)d_in[8];
    const float* xh2h_b = (const float*)d_in[9];
    const float* out_w  = (const float*)d_in[10];
    const float* out_b  = (const float*)d_in[11];
    float* out = (float*)d_out;

    float* ws   = (float*)d_ws;
    float* XI   = ws + OFF_XI;
    float* P    = ws + OFF_P;
    float* hbuf = ws + OFF_HBUF;
    float* abuf = ws + OFF_A;
    float* ybuf = ws + OFF_Y;
    ull*   bar  = (ull*)(ws + OFF_BAR);

    hipMemsetAsync(bar, 0, 2048, stream);
    hipMemcpyAsync(hbuf, h0, H * sizeof(float), hipMemcpyDeviceToDevice, stream);

    // XI = x @ inp_w^T + inp_b        [512,2048]
    gemm_nt<<<dim3(H / 64, T_STEPS / 128), 256, 0, stream>>>(
        x, IN_DIM, inp_w, IN_DIM, inp_b, XI, H, IN_DIM);
    // P = XI @ l1_w[:, :2048]^T + l1_b   [512,4096]
    gemm_nt<<<dim3(H2 / 64, T_STEPS / 128), 256, 0, stream>>>(
        XI, H, l1_w, H2, l1_b, P, H2, H);

    {
        void* args[] = {
            (void*)&l1_w, (void*)&l2_w, (void*)&l2_b,
            (void*)&xh2h_w, (void*)&xh2h_b,
            (void*)&XI, (void*)&P, (void*)&hbuf, (void*)&abuf, (void*)&ybuf,
            (void*)&bar
        };
        hipLaunchCooperativeKernel((const void*)rnn_seq, dim3(NWG), dim3(NTHR),
                                   args, 0, stream);
    }

    // ys = H' @ out_w^T + out_b       [512,1024]
    gemm_nt<<<dim3(OUT_DIM / 64, T_STEPS / 128), 256, 0, stream>>>(
        hbuf + H, H, out_w, H, out_b, out, OUT_DIM, H);
    hipMemcpyAsync(out + (size_t)T_STEPS * OUT_DIM, hbuf + (size_t)T_STEPS * H,
                   H * sizeof(float), hipMemcpyDeviceToDevice, stream);
}